// Round 1
// baseline (491.875 us; speedup 1.0000x reference)
//
#include <hip/hip_runtime.h>
#include <hip/hip_bf16.h>
#include <cstdint>
#include <cstddef>

// Problem constants (T,B,D,H,L = 1024,64,512,512,2)
#define T_DIM 1024
#define B_DIM 64
#define D_DIM 512
#define H_DIM 512
#define TBROWS (T_DIM * B_DIM)          // 65536 GEMM rows
#define BH (B_DIM * H_DIM)              // 32768
#define TBH ((size_t)T_DIM * (size_t)BH) // 33554432 elements

typedef __bf16 bf16x8 __attribute__((ext_vector_type(8)));
typedef float floatx4 __attribute__((ext_vector_type(4)));

// ---------------------------------------------------------------------------
// async global->LDS, 16B per lane. LDS dest is wave-uniform base + lane*16.
// ---------------------------------------------------------------------------
__device__ __forceinline__ void async_load16(const void* g, void* l) {
  __builtin_amdgcn_global_load_lds(
      (const __attribute__((address_space(1))) unsigned int*)g,
      (__attribute__((address_space(3))) unsigned int*)l,
      16, 0, 0);
}

// ---------------------------------------------------------------------------
// f32 -> bf16 conversion, 8 elements/thread (vectorized)
// ---------------------------------------------------------------------------
__global__ __launch_bounds__(256) void cvt_bf16_kernel(
    const float* __restrict__ in, __bf16* __restrict__ out, long n) {
  long i = ((long)blockIdx.x * 256 + threadIdx.x) * 8;
  if (i + 8 <= n) {
    const float4 a = *(const float4*)(in + i);
    const float4 b = *(const float4*)(in + i + 4);
    bf16x8 v;
    v[0] = (__bf16)a.x; v[1] = (__bf16)a.y; v[2] = (__bf16)a.z; v[3] = (__bf16)a.w;
    v[4] = (__bf16)b.x; v[5] = (__bf16)b.y; v[6] = (__bf16)b.z; v[7] = (__bf16)b.w;
    *(bf16x8*)(out + i) = v;
  }
}

// ---------------------------------------------------------------------------
// Fused weight: W[h,d] = sum_e w0[h,e] * fc_w[e,d]   (512x512x512, tiny)
// one h per block-pair; d coalesced; w0[h,e] is block-uniform (scalar load)
// ---------------------------------------------------------------------------
__global__ __launch_bounds__(256) void fuse_w_kernel(
    const float* __restrict__ w0, const float* __restrict__ fc_w,
    __bf16* __restrict__ W) {
  const int h = blockIdx.x >> 1;
  const int d = ((blockIdx.x & 1) << 8) + threadIdx.x;
  float a0 = 0.f, a1 = 0.f, a2 = 0.f, a3 = 0.f;
  for (int e = 0; e < D_DIM; e += 4) {
    a0 = fmaf(w0[h * D_DIM + e + 0], fc_w[(size_t)(e + 0) * D_DIM + d], a0);
    a1 = fmaf(w0[h * D_DIM + e + 1], fc_w[(size_t)(e + 1) * D_DIM + d], a1);
    a2 = fmaf(w0[h * D_DIM + e + 2], fc_w[(size_t)(e + 2) * D_DIM + d], a2);
    a3 = fmaf(w0[h * D_DIM + e + 3], fc_w[(size_t)(e + 3) * D_DIM + d], a3);
  }
  W[(size_t)h * D_DIM + d] = (__bf16)((a0 + a1) + (a2 + a3));
}

// Combined bias: bc[h] = b0[h] + sum_e w0[h,e]*fc_b[e]
__global__ __launch_bounds__(256) void bcomb_kernel(
    const float* __restrict__ w0, const float* __restrict__ fc_b,
    const float* __restrict__ b0, float* __restrict__ bc) {
  const int h = blockIdx.x * 256 + threadIdx.x;
  float acc = b0[h];
  for (int e = 0; e < D_DIM; ++e)
    acc = fmaf(w0[(size_t)h * D_DIM + e], fc_b[e], acc);
  bc[h] = acc;
}

// ---------------------------------------------------------------------------
// NT bf16 GEMM: C[m,n] = sum_k A[m,k]*Bm[n,k] + bias[n]
// m97 structure: 128x128 tile, BK=32, 4 waves (2x2 of 64x64), 16x16x32 MFMA,
// global_load_lds width 16.
// ---------------------------------------------------------------------------
#define BM 128
#define BN 128
#define BK 32

__global__ __launch_bounds__(256) void gemm_bt_bias(
    const __bf16* __restrict__ A,   // [M,K] row-major
    const __bf16* __restrict__ Bm,  // [N,K] row-major
    const float* __restrict__ bias, // [N]
    float* __restrict__ C,          // [M,N] row-major
    int M, int N, int K) {
  __shared__ __bf16 As[BM * BK]; // 8 KB, contiguous lane order for load_lds
  __shared__ __bf16 Bs[BN * BK]; // 8 KB

  const int tid = threadIdx.x;
  const int lane = tid & 63;
  const int wave = tid >> 6;
  const int nb = N / BN;
  const int bm = blockIdx.x / nb;
  const int bn = blockIdx.x % nb;
  const int m0 = bm * BM, n0 = bn * BN;

  floatx4 zero = {0.f, 0.f, 0.f, 0.f};
  floatx4 acc[4][4];
#pragma unroll
  for (int i = 0; i < 4; i++)
#pragma unroll
    for (int j = 0; j < 4; j++) acc[i][j] = zero;

  // staging: 16B unit e = (wave*2+j)*64 + lane; row = e>>2; col8 = (e&3)*8
  const int e0 = (wave * 2 + 0) * 64 + lane;
  const int e1 = (wave * 2 + 1) * 64 + lane;
  const int r0 = e0 >> 2, c0 = (e0 & 3) * 8;
  const int r1 = e1 >> 2, c1 = (e1 & 3) * 8;

  // compute-side fragment indices
  const int tm = (wave >> 1) * 64;
  const int tn = (wave & 1) * 64;
  const int lrow = lane & 15;
  const int lk = (lane >> 4) * 8;

  for (int k0 = 0; k0 < K; k0 += BK) {
    async_load16(&A[(size_t)(m0 + r0) * K + k0 + c0], &As[(wave * 2 + 0) * 512]);
    async_load16(&A[(size_t)(m0 + r1) * K + k0 + c1], &As[(wave * 2 + 1) * 512]);
    async_load16(&Bm[(size_t)(n0 + r0) * K + k0 + c0], &Bs[(wave * 2 + 0) * 512]);
    async_load16(&Bm[(size_t)(n0 + r1) * K + k0 + c1], &Bs[(wave * 2 + 1) * 512]);
    __syncthreads(); // drains vmcnt (load_lds) + barrier

    bf16x8 af[4], bfr[4];
#pragma unroll
    for (int i = 0; i < 4; i++) {
      af[i]  = *(const bf16x8*)&As[(tm + i * 16 + lrow) * BK + lk];
      bfr[i] = *(const bf16x8*)&Bs[(tn + i * 16 + lrow) * BK + lk];
    }
#pragma unroll
    for (int i = 0; i < 4; i++)
#pragma unroll
      for (int j = 0; j < 4; j++)
        acc[i][j] = __builtin_amdgcn_mfma_f32_16x16x32_bf16(af[i], bfr[j],
                                                            acc[i][j], 0, 0, 0);
    __syncthreads(); // protect LDS before next stage
  }

  // Epilogue. C/D layout: col = lane&15, row = (lane>>4)*4 + reg
  const int ccol = lane & 15;
  const int crow = (lane >> 4) * 4;
  float bv[4];
#pragma unroll
  for (int j = 0; j < 4; j++) bv[j] = bias[n0 + tn + j * 16 + ccol];
#pragma unroll
  for (int i = 0; i < 4; i++) {
#pragma unroll
    for (int j = 0; j < 4; j++) {
      const size_t base =
          (size_t)(m0 + tm + i * 16 + crow) * N + (n0 + tn + j * 16 + ccol);
#pragma unroll
      for (int r = 0; r < 4; r++)
        C[base + (size_t)r * N] = acc[i][j][r] + bv[j];
    }
  }
}

// ---------------------------------------------------------------------------
// IndRNN scan: one thread per (b,h). h_t = relu(pre_t + u*h_{t-1}).
// Unroll 32: 32 independent loads in flight per lane for latency hiding.
// BF16OUT=true writes bf16 (feeds next GEMM); false writes f32 (final out,
// may alias pre: same-thread read-then-write is safe).
// ---------------------------------------------------------------------------
template <bool BF16OUT>
__global__ __launch_bounds__(64) void scan_kernel(
    const float* __restrict__ pre,  // [T, BH]
    const float* __restrict__ h0,   // [BH]
    const float* __restrict__ u,    // [H]
    void* __restrict__ outp,        // [T, BH] bf16 or f32
    float* __restrict__ hn) {       // [BH]
  const int idx = blockIdx.x * 64 + threadIdx.x;
  const float uu = u[idx & (H_DIM - 1)];
  float h = h0[idx];
  __bf16* ob = (__bf16*)outp;
  float* of = (float*)outp;
  for (int t0 = 0; t0 < T_DIM; t0 += 32) {
    float v[32];
#pragma unroll
    for (int s = 0; s < 32; s++) v[s] = pre[(size_t)(t0 + s) * BH + idx];
#pragma unroll
    for (int s = 0; s < 32; s++) {
      h = fmaxf(fmaf(uu, h, v[s]), 0.0f);
      if (BF16OUT)
        ob[(size_t)(t0 + s) * BH + idx] = (__bf16)h;
      else
        of[(size_t)(t0 + s) * BH + idx] = h;
    }
  }
  hn[idx] = h;
}

// ---------------------------------------------------------------------------
extern "C" void kernel_launch(void* const* d_in, const int* in_sizes, int n_in,
                              void* d_out, int out_size, void* d_ws,
                              size_t ws_size, hipStream_t stream) {
  (void)in_sizes; (void)n_in; (void)out_size; (void)ws_size;
  const float* x      = (const float*)d_in[0]; // [T,B,D]
  const float* hidden = (const float*)d_in[1]; // [L,B,H]
  const float* fc_w   = (const float*)d_in[2]; // [D,D]
  const float* fc_b   = (const float*)d_in[3]; // [D]
  const float* w0     = (const float*)d_in[4]; // [H,D]
  const float* b0     = (const float*)d_in[5]; // [H]
  const float* u0     = (const float*)d_in[6]; // [H]
  const float* w1     = (const float*)d_in[7]; // [H,H]
  const float* b1     = (const float*)d_in[8]; // [H]
  const float* u1     = (const float*)d_in[9]; // [H]
  float* out = (float*)d_out;

  // workspace layout (~65.5 MB):
  char* ws = (char*)d_ws;
  __bf16* xbf   = (__bf16*)ws;                             // 64 MB; later out0_bf16
  __bf16* Wc    = (__bf16*)(ws + TBH * 2);                 // 512 KB fused weight
  __bf16* w1bf  = (__bf16*)(ws + TBH * 2 + 512 * 1024);    // 512 KB
  float*  bcomb = (float*)(ws + TBH * 2 + 1024 * 1024);    // 2 KB

  // d_out[0..TBH) doubles as the f32 `pre` scratch; hn lives after it.
  float* pre = out;
  float* hn  = out + TBH;

  // 1) x -> bf16
  cvt_bf16_kernel<<<(int)(TBH / (256 * 8)), 256, 0, stream>>>(x, xbf, (long)TBH);
  // 2) w1 -> bf16
  cvt_bf16_kernel<<<(H_DIM * H_DIM) / (256 * 8), 256, 0, stream>>>(
      w1, w1bf, (long)(H_DIM * H_DIM));
  // 3) fused fc+w0 weight (f32 accumulate, bf16 out)
  fuse_w_kernel<<<H_DIM * 2, 256, 0, stream>>>(w0, fc_w, Wc);
  // 4) combined bias
  bcomb_kernel<<<H_DIM / 256, 256, 0, stream>>>(w0, fc_b, b0, bcomb);
  // 5) pre0 = x @ Wc^T + bcomb   -> d_out scratch
  gemm_bt_bias<<<(TBROWS / BM) * (H_DIM / BN), 256, 0, stream>>>(
      xbf, Wc, bcomb, pre, TBROWS, H_DIM, D_DIM);
  // 6) layer-0 scan: out0(bf16) -> xbf region; h0_final -> hn[0]
  scan_kernel<true><<<BH / 64, 64, 0, stream>>>(pre, hidden, u0, (void*)xbf, hn);
  // 7) pre1 = out0 @ w1^T + b1  -> d_out scratch (overwrite)
  gemm_bt_bias<<<(TBROWS / BM) * (H_DIM / BN), 256, 0, stream>>>(
      xbf, w1bf, b1, pre, TBROWS, H_DIM, H_DIM);
  // 8) layer-1 scan in place: out1(f32) over pre; h1_final -> hn[1]
  scan_kernel<false><<<BH / 64, 64, 0, stream>>>(pre, hidden + BH, u1,
                                                 (void*)pre, hn + BH);
}

// Round 2
// 468.050 us; speedup vs baseline: 1.0509x; 1.0509x over previous
//
#include <hip/hip_runtime.h>
#include <hip/hip_bf16.h>
#include <cstdint>
#include <cstddef>

// Problem constants (T,B,D,H,L = 1024,64,512,512,2)
#define T_DIM 1024
#define B_DIM 64
#define D_DIM 512
#define H_DIM 512
#define TBROWS (T_DIM * B_DIM)           // 65536 GEMM rows
#define BH (B_DIM * H_DIM)               // 32768
#define TBH ((size_t)T_DIM * (size_t)BH) // 33554432 elements

typedef __bf16 bf16x8 __attribute__((ext_vector_type(8)));
typedef float floatx4 __attribute__((ext_vector_type(4)));

// ---------------------------------------------------------------------------
// async global->LDS, 16B per lane. LDS dest is wave-uniform base + lane*16.
// ---------------------------------------------------------------------------
__device__ __forceinline__ void async_load16(const void* g, void* l) {
  __builtin_amdgcn_global_load_lds(
      (const __attribute__((address_space(1))) unsigned int*)g,
      (__attribute__((address_space(3))) unsigned int*)l,
      16, 0, 0);
}

// ---------------------------------------------------------------------------
// f32 -> bf16 conversion (used only for w1, 512x512)
// ---------------------------------------------------------------------------
__global__ __launch_bounds__(256) void cvt_bf16_kernel(
    const float* __restrict__ in, __bf16* __restrict__ out, long n) {
  long i = ((long)blockIdx.x * 256 + threadIdx.x) * 8;
  if (i + 8 <= n) {
    const float4 a = *(const float4*)(in + i);
    const float4 b = *(const float4*)(in + i + 4);
    bf16x8 v;
    v[0] = (__bf16)a.x; v[1] = (__bf16)a.y; v[2] = (__bf16)a.z; v[3] = (__bf16)a.w;
    v[4] = (__bf16)b.x; v[5] = (__bf16)b.y; v[6] = (__bf16)b.z; v[7] = (__bf16)b.w;
    *(bf16x8*)(out + i) = v;
  }
}

// ---------------------------------------------------------------------------
// Fused weight: W[h,d] = sum_e w0[h,e] * fc_w[e,d]  (512^3, tiny)
// ---------------------------------------------------------------------------
__global__ __launch_bounds__(256) void fuse_w_kernel(
    const float* __restrict__ w0, const float* __restrict__ fc_w,
    __bf16* __restrict__ W) {
  const int h = blockIdx.x >> 1;
  const int d = ((blockIdx.x & 1) << 8) + threadIdx.x;
  float a0 = 0.f, a1 = 0.f, a2 = 0.f, a3 = 0.f;
  for (int e = 0; e < D_DIM; e += 4) {
    a0 = fmaf(w0[h * D_DIM + e + 0], fc_w[(size_t)(e + 0) * D_DIM + d], a0);
    a1 = fmaf(w0[h * D_DIM + e + 1], fc_w[(size_t)(e + 1) * D_DIM + d], a1);
    a2 = fmaf(w0[h * D_DIM + e + 2], fc_w[(size_t)(e + 2) * D_DIM + d], a2);
    a3 = fmaf(w0[h * D_DIM + e + 3], fc_w[(size_t)(e + 3) * D_DIM + d], a3);
  }
  W[(size_t)h * D_DIM + d] = (__bf16)((a0 + a1) + (a2 + a3));
}

// Combined bias: bc[h] = b0[h] + sum_e w0[h,e]*fc_b[e]
__global__ __launch_bounds__(256) void bcomb_kernel(
    const float* __restrict__ w0, const float* __restrict__ fc_b,
    const float* __restrict__ b0, float* __restrict__ bc) {
  const int h = blockIdx.x * 256 + threadIdx.x;
  float acc = b0[h];
  for (int e = 0; e < D_DIM; ++e)
    acc = fmaf(w0[(size_t)h * D_DIM + e], fc_b[e], acc);
  bc[h] = acc;
}

#define BM 128
#define BN 128
#define BK 32

// ---------------------------------------------------------------------------
// GEMM1: A is f32 [M,K]; B bf16 [N,K]; C bf16 [M,N] = A@B^T + bias.
// A staged to LDS as f32 via global_load_lds(16B = 4 floats) with an XOR
// column-quad swizzle (slot = (cq + row) & 7) to break the 16-way bank
// conflict that a naive f32 row-major tile would have on the b128 reads.
// ---------------------------------------------------------------------------
__global__ __launch_bounds__(256) void gemm_a32_bt_bias(
    const float* __restrict__ A,    // [M,K] f32 row-major
    const __bf16* __restrict__ Bm,  // [N,K] bf16 row-major
    const float* __restrict__ bias, // [N]
    __bf16* __restrict__ C,         // [M,N] bf16 row-major
    int M, int N, int K) {
  __shared__ float Asf[BM * BK];  // 16 KB
  __shared__ __bf16 Bs[BN * BK];  // 8 KB

  const int tid = threadIdx.x;
  const int lane = tid & 63;
  const int wave = tid >> 6;
  const int nb = N / BN;
  const int bm = blockIdx.x / nb;
  const int bn = blockIdx.x % nb;
  const int m0 = bm * BM, n0 = bn * BN;

  floatx4 zero = {0.f, 0.f, 0.f, 0.f};
  floatx4 acc[4][4];
#pragma unroll
  for (int i = 0; i < 4; i++)
#pragma unroll
    for (int j = 0; j < 4; j++) acc[i][j] = zero;

  // B staging map (bf16): unit e covers row e>>2, cols (e&3)*8..+7
  const int e0 = (wave * 2 + 0) * 64 + lane;
  const int e1 = (wave * 2 + 1) * 64 + lane;
  const int br0 = e0 >> 2, bc0 = (e0 & 3) * 8;
  const int br1 = e1 >> 2, bc1 = (e1 & 3) * 8;

  // A staging map (f32, swizzled): unit u -> row u>>3, slot u&7,
  // stored col-quad cq = (slot - row) & 7
  int ar[4], ac[4], abase[4];
#pragma unroll
  for (int j = 0; j < 4; j++) {
    const int u = j * 256 + wave * 64 + lane;
    ar[j] = u >> 3;
    const int s = u & 7;
    ac[j] = ((s - ar[j]) & 7) * 4;
    abase[j] = (j * 256 + wave * 64) * 4; // float index of wave-uniform base
  }

  const int tm = (wave >> 1) * 64;
  const int tn = (wave & 1) * 64;
  const int lrow = lane & 15;
  const int lk = (lane >> 4) * 8;

  for (int k0 = 0; k0 < K; k0 += BK) {
#pragma unroll
    for (int j = 0; j < 4; j++)
      async_load16(&A[(size_t)(m0 + ar[j]) * K + k0 + ac[j]], &Asf[abase[j]]);
    async_load16(&Bm[(size_t)(n0 + br0) * K + k0 + bc0], &Bs[(wave * 2 + 0) * 512]);
    async_load16(&Bm[(size_t)(n0 + br1) * K + k0 + bc1], &Bs[(wave * 2 + 1) * 512]);
    __syncthreads();

    bf16x8 af[4], bfr[4];
#pragma unroll
    for (int i = 0; i < 4; i++) {
      const int row = tm + i * 16 + lrow;
      const int s0 = ((lk >> 2) + row) & 7;
      const int s1 = ((lk >> 2) + 1 + row) & 7;
      const float4 f0 = *(const float4*)&Asf[(row * 8 + s0) * 4];
      const float4 f1 = *(const float4*)&Asf[(row * 8 + s1) * 4];
      bf16x8 v;
      v[0] = (__bf16)f0.x; v[1] = (__bf16)f0.y; v[2] = (__bf16)f0.z; v[3] = (__bf16)f0.w;
      v[4] = (__bf16)f1.x; v[5] = (__bf16)f1.y; v[6] = (__bf16)f1.z; v[7] = (__bf16)f1.w;
      af[i] = v;
      bfr[i] = *(const bf16x8*)&Bs[(tn + i * 16 + lrow) * BK + lk];
    }
#pragma unroll
    for (int i = 0; i < 4; i++)
#pragma unroll
      for (int j = 0; j < 4; j++)
        acc[i][j] = __builtin_amdgcn_mfma_f32_16x16x32_bf16(af[i], bfr[j],
                                                            acc[i][j], 0, 0, 0);
    __syncthreads();
  }

  // Epilogue: C/D layout col = lane&15, row = (lane>>4)*4 + reg; bf16 out
  const int ccol = lane & 15;
  const int crow = (lane >> 4) * 4;
  float bv[4];
#pragma unroll
  for (int j = 0; j < 4; j++) bv[j] = bias[n0 + tn + j * 16 + ccol];
#pragma unroll
  for (int i = 0; i < 4; i++) {
#pragma unroll
    for (int j = 0; j < 4; j++) {
      const size_t base =
          (size_t)(m0 + tm + i * 16 + crow) * N + (n0 + tn + j * 16 + ccol);
#pragma unroll
      for (int r = 0; r < 4; r++)
        C[base + (size_t)r * N] = (__bf16)(acc[i][j][r] + bv[j]);
    }
  }
}

// ---------------------------------------------------------------------------
// GEMM2: bf16 A, bf16 B, bf16 C (m97 structure, unchanged compute path)
// ---------------------------------------------------------------------------
__global__ __launch_bounds__(256) void gemm_bt_bias(
    const __bf16* __restrict__ A,   // [M,K]
    const __bf16* __restrict__ Bm,  // [N,K]
    const float* __restrict__ bias, // [N]
    __bf16* __restrict__ C,         // [M,N]
    int M, int N, int K) {
  __shared__ __bf16 As[BM * BK];
  __shared__ __bf16 Bs[BN * BK];

  const int tid = threadIdx.x;
  const int lane = tid & 63;
  const int wave = tid >> 6;
  const int nb = N / BN;
  const int bm = blockIdx.x / nb;
  const int bn = blockIdx.x % nb;
  const int m0 = bm * BM, n0 = bn * BN;

  floatx4 zero = {0.f, 0.f, 0.f, 0.f};
  floatx4 acc[4][4];
#pragma unroll
  for (int i = 0; i < 4; i++)
#pragma unroll
    for (int j = 0; j < 4; j++) acc[i][j] = zero;

  const int e0 = (wave * 2 + 0) * 64 + lane;
  const int e1 = (wave * 2 + 1) * 64 + lane;
  const int r0 = e0 >> 2, c0 = (e0 & 3) * 8;
  const int r1 = e1 >> 2, c1 = (e1 & 3) * 8;

  const int tm = (wave >> 1) * 64;
  const int tn = (wave & 1) * 64;
  const int lrow = lane & 15;
  const int lk = (lane >> 4) * 8;

  for (int k0 = 0; k0 < K; k0 += BK) {
    async_load16(&A[(size_t)(m0 + r0) * K + k0 + c0], &As[(wave * 2 + 0) * 512]);
    async_load16(&A[(size_t)(m0 + r1) * K + k0 + c1], &As[(wave * 2 + 1) * 512]);
    async_load16(&Bm[(size_t)(n0 + r0) * K + k0 + c0], &Bs[(wave * 2 + 0) * 512]);
    async_load16(&Bm[(size_t)(n0 + r1) * K + k0 + c1], &Bs[(wave * 2 + 1) * 512]);
    __syncthreads();

    bf16x8 af[4], bfr[4];
#pragma unroll
    for (int i = 0; i < 4; i++) {
      af[i]  = *(const bf16x8*)&As[(tm + i * 16 + lrow) * BK + lk];
      bfr[i] = *(const bf16x8*)&Bs[(tn + i * 16 + lrow) * BK + lk];
    }
#pragma unroll
    for (int i = 0; i < 4; i++)
#pragma unroll
      for (int j = 0; j < 4; j++)
        acc[i][j] = __builtin_amdgcn_mfma_f32_16x16x32_bf16(af[i], bfr[j],
                                                            acc[i][j], 0, 0, 0);
    __syncthreads();
  }

  const int ccol = lane & 15;
  const int crow = (lane >> 4) * 4;
  float bv[4];
#pragma unroll
  for (int j = 0; j < 4; j++) bv[j] = bias[n0 + tn + j * 16 + ccol];
#pragma unroll
  for (int i = 0; i < 4; i++) {
#pragma unroll
    for (int j = 0; j < 4; j++) {
      const size_t base =
          (size_t)(m0 + tm + i * 16 + crow) * N + (n0 + tn + j * 16 + ccol);
#pragma unroll
      for (int r = 0; r < 4; r++)
        C[base + (size_t)r * N] = (__bf16)(acc[i][j][r] + bv[j]);
    }
  }
}

// ---------------------------------------------------------------------------
// IndRNN scan: one thread per (b,h); pre is bf16. Software prefetch: chunk
// t0+32 loads issue before the dependent compute/store of chunk t0, keeping
// 32 loads in flight at only 2 waves/CU.
// ---------------------------------------------------------------------------
template <bool BF16OUT>
__global__ __launch_bounds__(64) void scan_kernel(
    const __bf16* __restrict__ pre, // [T, BH] bf16
    const float* __restrict__ h0,   // [BH]
    const float* __restrict__ u,    // [H]
    void* __restrict__ outp,        // [T, BH] bf16 or f32
    float* __restrict__ hn) {       // [BH]
  const int idx = blockIdx.x * 64 + threadIdx.x;
  const float uu = u[idx & (H_DIM - 1)];
  float h = h0[idx];
  __bf16* __restrict__ ob = (__bf16*)outp;
  float* __restrict__ of = (float*)outp;

  float v[32];
#pragma unroll
  for (int s = 0; s < 32; s++) v[s] = (float)pre[(size_t)s * BH + idx];

  for (int t0 = 0; t0 < T_DIM; t0 += 32) {
    float w[32];
    const bool more = (t0 + 32) < T_DIM;
    if (more) {
#pragma unroll
      for (int s = 0; s < 32; s++)
        w[s] = (float)pre[(size_t)(t0 + 32 + s) * BH + idx];
    }
#pragma unroll
    for (int s = 0; s < 32; s++) {
      h = fmaxf(fmaf(uu, h, v[s]), 0.0f);
      if (BF16OUT)
        ob[(size_t)(t0 + s) * BH + idx] = (__bf16)h;
      else
        of[(size_t)(t0 + s) * BH + idx] = h;
    }
    if (more) {
#pragma unroll
      for (int s = 0; s < 32; s++) v[s] = w[s];
    }
  }
  hn[idx] = h;
}

// ---------------------------------------------------------------------------
extern "C" void kernel_launch(void* const* d_in, const int* in_sizes, int n_in,
                              void* d_out, int out_size, void* d_ws,
                              size_t ws_size, hipStream_t stream) {
  (void)in_sizes; (void)n_in; (void)out_size; (void)ws_size;
  const float* x      = (const float*)d_in[0]; // [T,B,D]
  const float* hidden = (const float*)d_in[1]; // [L,B,H]
  const float* fc_w   = (const float*)d_in[2]; // [D,D]
  const float* fc_b   = (const float*)d_in[3]; // [D]
  const float* w0     = (const float*)d_in[4]; // [H,D]
  const float* b0     = (const float*)d_in[5]; // [H]
  const float* u0     = (const float*)d_in[6]; // [H]
  const float* w1     = (const float*)d_in[7]; // [H,H]
  const float* b1     = (const float*)d_in[8]; // [H]
  const float* u1     = (const float*)d_in[9]; // [H]
  float* out = (float*)d_out;

  // workspace (~130 MB of ~537 MB): pre (bf16, reused for pre0 then pre1),
  // out0 (bf16), small weight buffers.
  char* ws = (char*)d_ws;
  __bf16* pre   = (__bf16*)ws;                      // 64 MB
  __bf16* out0  = (__bf16*)(ws + TBH * 2);          // 64 MB
  char*   tail  = ws + 2 * TBH * 2;
  __bf16* Wc    = (__bf16*)tail;                    // 512 KB
  __bf16* w1bf  = (__bf16*)(tail + 512 * 1024);     // 512 KB
  float*  bcomb = (float*)(tail + 1024 * 1024);     // 2 KB

  float* hn = out + TBH; // [2, BH] after out1

  // 1) w1 -> bf16
  cvt_bf16_kernel<<<(H_DIM * H_DIM) / (256 * 8), 256, 0, stream>>>(
      w1, w1bf, (long)(H_DIM * H_DIM));
  // 2) fused fc+w0 weight
  fuse_w_kernel<<<H_DIM * 2, 256, 0, stream>>>(w0, fc_w, Wc);
  // 3) combined bias
  bcomb_kernel<<<H_DIM / 256, 256, 0, stream>>>(w0, fc_b, b0, bcomb);
  // 4) pre0 = x(f32) @ Wc^T + bcomb  -> bf16
  gemm_a32_bt_bias<<<(TBROWS / BM) * (H_DIM / BN), 256, 0, stream>>>(
      x, Wc, bcomb, pre, TBROWS, H_DIM, D_DIM);
  // 5) layer-0 scan: out0 (bf16), hn[0]
  scan_kernel<true><<<BH / 64, 64, 0, stream>>>(pre, hidden, u0, (void*)out0, hn);
  // 6) pre1 = out0 @ w1^T + b1 -> bf16 (reuse pre buffer)
  gemm_bt_bias<<<(TBROWS / BM) * (H_DIM / BN), 256, 0, stream>>>(
      out0, w1bf, b1, pre, TBROWS, H_DIM, H_DIM);
  // 7) layer-1 scan: out1 (f32) -> d_out, hn[1]
  scan_kernel<false><<<BH / 64, 64, 0, stream>>>(pre, hidden + BH, u1,
                                                 (void*)out, hn + BH);
}